// Round 5
// baseline (234.983 us; speedup 1.0000x reference)
//
#include <hip/hip_runtime.h>

// Problem constants (B=8, H=4096, C=512, GROUPS=4)
constexpr int D         = 128;        // d = C/GROUPS
constexpr int NE        = 512;        // n_embed
constexpr int NROWS     = 131072;     // B*H*GROUPS
constexpr int CC        = 512;        // C
constexpr int OUT_ELEMS = 16777216;   // MROWS*CC

// ws layout (bytes):
//   [0]                 : float diff accumulator
//   [1024, +2048)       : entab - ||e_j||^2 fp32, 512 floats
//   [4096, +262144)     : esw - 16 chunks x 16384 B:
//        [0,8192)   Eh : fp16(-2E), MFMA A-frag layout
//        [8192,16384) El: fp16((-2E - Eh)*2048)
//   [266240, +4194304)  : P[4][512][512] fp32

using half8  = __attribute__((ext_vector_type(8))) _Float16;
using f32x16 = __attribute__((ext_vector_type(16))) float;

// fp16 min normal: leading term below this is zeroed so the (possibly
// flushed-by-MFMA) denormal carries nothing; residual then holds it all.
#define F16_MINNORM 6.103515625e-05f

// plain 2-term f16 split of 8 floats: v = t1 + t2/2048 (+ ~2^-21 rel)
__device__ __forceinline__ void split8(float4 a, float4 b,
                                       half8& t1, half8& t2) {
    float v[8] = {a.x, a.y, a.z, a.w, b.x, b.y, b.z, b.w};
#pragma unroll
    for (int i = 0; i < 8; i++) {
        float vc = (__builtin_fabsf(v[i]) < F16_MINNORM) ? 0.0f : v[i];
        _Float16 h = (_Float16)vc;
        float r = v[i] - (float)h;
        t1[i] = h;
        t2[i] = (_Float16)(r * 2048.0f);
    }
}

// ---------------------------------------------------------------------------
// Kernel 0 (fused): blocks [0,64)  = MFMA pgemm  P[g][j][c] = sum_k E[j,k]*W[c,g*128+k]
//                   blocks [64,80) = eprep (fp16 split of -2E + ||e||^2 table)
// pgemm converts E and W to 2-term f16 fragments IN-WAVE (no esw dependency,
// so no cross-block ordering needed) and uses the same 3-MFMA scheme as the
// argmin kernel: P = accA + accB * 2^-11, err ~2^-21 rel. 256 wave-jobs
// (g x cblk x quad), each = 32 W-rows x 128 codes x K=128.
__launch_bounds__(256, 4)
__global__ void prep_kernel(const float* __restrict__ embed,
                            const float* __restrict__ projw,
                            unsigned short* __restrict__ esw,
                            float* __restrict__ entab,
                            float* __restrict__ ws_diff,
                            float* __restrict__ P) {
    const int tid = threadIdx.x;

    if (blockIdx.x >= 64) {
        // ---- eprep body ----
        const int chunk = blockIdx.x - 64;
        const int cl = tid >> 3;    // code in chunk (0..31) == A-row == lane&31
        const int seg = tid & 7;    // k-group of 16 (== kk)
        const float* src = embed + (size_t)(chunk * 32 + cl) * D + seg * 16;
        unsigned short* cb = esw + (size_t)chunk * 8192;  // shorts per chunk

        float ss = 0.f;
#pragma unroll
        for (int g2 = 0; g2 < 2; g2++) {   // g2 == h5 (k-half of the MFMA slice)
            float4 a = ((const float4*)src)[g2 * 2 + 0];
            float4 b = ((const float4*)src)[g2 * 2 + 1];
            float v[8] = {a.x, a.y, a.z, a.w, b.x, b.y, b.z, b.w};
            half8 t1, t2;
#pragma unroll
            for (int i = 0; i < 8; i++) {
                ss += v[i] * v[i];
                float m2 = -2.0f * v[i];
                float m2c = (__builtin_fabsf(m2) < F16_MINNORM) ? 0.0f : m2;
                _Float16 h = (_Float16)m2c;
                float r = m2 - (float)h;
                t1[i] = h;
                t2[i] = (_Float16)(r * 2048.0f);   // scaled residual, fp16-normal
            }
            const int idx = seg * 512 + g2 * 256 + cl * 8;
            *(half8*)(cb + idx) = t1;          // Eh
            *(half8*)(cb + 4096 + idx) = t2;   // El
        }
        ss += __shfl_down(ss, 4, 8);
        ss += __shfl_down(ss, 2, 8);
        ss += __shfl_down(ss, 1, 8);
        if (seg == 0) entab[chunk * 32 + cl] = ss;
        if (chunk == 0 && tid == 0) ws_diff[0] = 0.0f;
        return;
    }

    // ---- MFMA pgemm: wave-job = (g, cblk, quad) ----
    const int lane = tid & 63;
    const int wave = tid >> 6;
    const int h5 = lane >> 5, l5 = lane & 31;
    const int job  = blockIdx.x * 4 + wave;   // 0..255
    const int g    = job >> 6;                // 0..3
    const int cblk = (job >> 2) & 15;         // 0..15 (32 c's each)
    const int quad = job & 3;                 // 0..3  (4 chunks of 32 codes)

    // W fragments (B-operand): lane holds W row (cblk*32+l5), k = kk*16+h5*8+j
    half8 wh[8], wl[8];
    {
        const float* wr = projw + (size_t)(cblk * 32 + l5) * CC + g * D + h5 * 8;
#pragma unroll
        for (int kk = 0; kk < 8; kk++) {
            float4 a = *(const float4*)(wr + kk * 16);
            float4 b = *(const float4*)(wr + kk * 16 + 4);
            split8(a, b, wh[kk], wl[kk]);
        }
    }

#pragma unroll 1
    for (int q = 0; q < 4; q++) {
        const int ch = quad * 4 + q;
        // E fragments (A-operand): lane holds code row (ch*32+l5), same k map
        half8 eh[8], el[8];
        {
            const float* er = embed + (size_t)(ch * 32 + l5) * D + h5 * 8;
#pragma unroll
            for (int kk = 0; kk < 8; kk++) {
                float4 a = *(const float4*)(er + kk * 16);
                float4 b = *(const float4*)(er + kk * 16 + 4);
                split8(a, b, eh[kk], el[kk]);
            }
        }
        f32x16 accA = (f32x16)(0.0f), accB = (f32x16)(0.0f);
#pragma unroll
        for (int kk = 0; kk < 8; kk++) {
            accA = __builtin_amdgcn_mfma_f32_32x32x16_f16(eh[kk], wh[kk], accA, 0, 0, 0);
            accB = __builtin_amdgcn_mfma_f32_32x32x16_f16(eh[kk], wl[kk], accB, 0, 0, 0);
            accB = __builtin_amdgcn_mfma_f32_32x32x16_f16(el[kk], wh[kk], accB, 0, 0, 0);
        }
        // C layout: row j = (r&3)+8*(r>>2)+4*h5, col c = l5 (coalesced stores)
#pragma unroll
        for (int r = 0; r < 16; r++) {
            const int jl = (r & 3) + 8 * (r >> 2) + 4 * h5;
            P[(size_t)g * 262144 + (size_t)(ch * 32 + jl) * CC + cblk * 32 + l5] =
                fmaf(accB[r], 4.8828125e-4f, accA[r]);
        }
    }
}

// ---------------------------------------------------------------------------
// Kernel 1: fused MFMA argmin + projection epilogue, T3/T4 pipelined staging,
// R=2 row-groups per wave: each wave owns 64 x-rows (grp0 rb0.., grp1 +128),
// so each staged E-fragment pair (2 ds_read_b128) feeds 6 MFMAs instead of 3;
// per-CU LDS reads, stage traffic and barrier count all halve. Counted
// s_waitcnt vmcnt(4) (NEVER 0 in-loop) + raw s_barrier keeps prefetch in
// flight across the barrier. No fence/ticket (rounds 1-3's ~100us lesson).
__global__ __launch_bounds__(256, 2)
void argmin_fused_kernel(const float* __restrict__ z,
                         const unsigned short* __restrict__ esw,
                         const float* __restrict__ entab,
                         const float* __restrict__ P,
                         const float* __restrict__ projb,
                         float* __restrict__ ws_diff,
                         float* __restrict__ ind_f,
                         float* __restrict__ out) {
    __shared__ __align__(16) unsigned char ebuf[3 * 16384];   // 3-slot chunk ring
    __shared__ __align__(16) float entab_s[512];
    const int tid = threadIdx.x;
    const int lane = tid & 63;
    const int wave = tid >> 6;
    const int h5 = lane >> 5, l5 = lane & 31;
    const int rb0 = blockIdx.x * 256 + wave * 32;   // grp0 rows
    const int rb1 = rb0 + 128;                      // grp1 rows

    // stage chunk c into ring slot b (16384 B; 4096 B per wave, 4 x 1024 B)
    // LDS dst is wave-uniform base; HW adds lane*16. Global src is per-lane.
    auto stage = [&](int c, int b) {
        const unsigned char* s = (const unsigned char*)esw + (size_t)c * 16384 +
                                 wave * 4096 + lane * 16;
        unsigned char* d = &ebuf[b * 16384 + wave * 4096];
#pragma unroll
        for (int it = 0; it < 4; it++)
            __builtin_amdgcn_global_load_lds(
                (const __attribute__((address_space(1))) unsigned int*)(s + it * 1024),
                (__attribute__((address_space(3))) unsigned int*)(d + it * 1024),
                16, 0, 0);
    };

    // ---- prologue: issue entab->LDS, stage(0), stage(1); then z load+convert.
    if (tid < 128)
        __builtin_amdgcn_global_load_lds(
            (const __attribute__((address_space(1))) unsigned int*)(entab + tid * 4),
            (__attribute__((address_space(3))) unsigned int*)(entab_s + tid * 4),
            16, 0, 0);
    stage(0, 0);
    stage(1, 1);

    // X fragments for both row-groups (B-frag: X[n=l5][k = kk*16 + h5*8 + j])
    half8 x1a[8], x2a[8], x1b[8], x2b[8];
    float xna = 0.f, xnb = 0.f;
    {
        const float* zr = z + (size_t)(rb0 + l5) * D + h5 * 8;
#pragma unroll
        for (int kk = 0; kk < 8; kk++) {
            float4 a = *(const float4*)(zr + kk * 16);
            float4 b = *(const float4*)(zr + kk * 16 + 4);
            xna += a.x*a.x + a.y*a.y + a.z*a.z + a.w*a.w +
                   b.x*b.x + b.y*b.y + b.z*b.z + b.w*b.w;
            split8(a, b, x1a[kk], x2a[kk]);
        }
        const float* zr2 = z + (size_t)(rb1 + l5) * D + h5 * 8;
#pragma unroll
        for (int kk = 0; kk < 8; kk++) {
            float4 a = *(const float4*)(zr2 + kk * 16);
            float4 b = *(const float4*)(zr2 + kk * 16 + 4);
            xnb += a.x*a.x + a.y*a.y + a.z*a.z + a.w*a.w +
                   b.x*b.x + b.y*b.y + b.z*b.z + b.w*b.w;
            split8(a, b, x1b[kk], x2b[kk]);
        }
    }

    float minva = 3.0e38f, minvb = 3.0e38f;
    int   minia = 0,       minib = 0;

    int bs = 0;                    // ring slot of chunk c
    int ts = 2;                    // ring slot of chunk c+2
#pragma unroll 1
    for (int c = 0; c < 16; c++) {
        // chunk c's stage loads done (leave c+1's 4 in flight); all-waves align
        if (c < 15) { asm volatile("s_waitcnt vmcnt(4)" ::: "memory"); }
        else        { asm volatile("s_waitcnt vmcnt(0)" ::: "memory"); }
        __builtin_amdgcn_s_barrier();
        __builtin_amdgcn_sched_barrier(0);
        // safe to overwrite slot ts (last read in compute(c-1), all waves past)
        if (c < 14) stage(c + 2, ts);

        const unsigned char* ldsb = &ebuf[bs * 16384];

        f32x16 accA0 = (f32x16)(0.0f), accB0 = (f32x16)(0.0f);
        f32x16 accA1 = (f32x16)(0.0f), accB1 = (f32x16)(0.0f);
#pragma unroll
        for (int kk = 0; kk < 8; kk++) {
            const int fo = kk * 1024 + h5 * 512 + l5 * 16;
            half8 e1 = *(const half8*)(ldsb + fo);
            half8 e2 = *(const half8*)(ldsb + 8192 + fo);
            accA0 = __builtin_amdgcn_mfma_f32_32x32x16_f16(e1, x1a[kk], accA0, 0, 0, 0);
            accB0 = __builtin_amdgcn_mfma_f32_32x32x16_f16(e1, x2a[kk], accB0, 0, 0, 0);
            accB0 = __builtin_amdgcn_mfma_f32_32x32x16_f16(e2, x1a[kk], accB0, 0, 0, 0);
            accA1 = __builtin_amdgcn_mfma_f32_32x32x16_f16(e1, x1b[kk], accA1, 0, 0, 0);
            accB1 = __builtin_amdgcn_mfma_f32_32x32x16_f16(e1, x2b[kk], accB1, 0, 0, 0);
            accB1 = __builtin_amdgcn_mfma_f32_32x32x16_f16(e2, x1b[kk], accB1, 0, 0, 0);
        }

        // ||e||^2 from LDS (shared by both row-groups)
        float4 enr[4];
#pragma unroll
        for (int u = 0; u < 4; u++)
            enr[u] = *(const float4*)&entab_s[c * 32 + h5 * 4 + u * 8];

        // scan: dist = accA + 2^-11 * accB + ||e||^2 ; monotone code order
        const int cb2 = c * 32 + h5 * 4;
#pragma unroll
        for (int r = 0; r < 16; r++) {
            const float en = ((const float*)&enr[r >> 2])[r & 3];
            const int cand = cb2 + (r & 3) + 8 * (r >> 2);
            float d0 = fmaf(accB0[r], 4.8828125e-4f, accA0[r]) + en;
            if (d0 < minva) { minva = d0; minia = cand; }  // strict < keeps first
            float d1 = fmaf(accB1[r], 4.8828125e-4f, accA1[r]) + en;
            if (d1 < minvb) { minvb = d1; minib = cand; }
        }
        bs = (bs == 2) ? 0 : bs + 1;
        ts = (ts == 2) ? 0 : ts + 1;
    }

    // merge the two half-wave code sets for the same x-row (col = lane&31)
    {
        float ov = __shfl_xor(minva, 32);
        int oi = __shfl_xor(minia, 32);
        if (ov < minva || (ov == minva && oi < minia)) { minva = ov; minia = oi; }
        float ov1 = __shfl_xor(minvb, 32);
        int oi1 = __shfl_xor(minib, 32);
        if (ov1 < minvb || (ov1 == minvb && oi1 < minib)) { minvb = ov1; minib = oi1; }
    }
    if (lane < 32) {
        ind_f[rb0 + l5] = (float)minia;
        ind_f[rb1 + l5] = (float)minib;
    }

    // ---- fused projection epilogue (wave-local, indices via shuffle) ----
    // wave owns out-rows [ob0, ob0+8) for grp0 and [ob0+32, +8) for grp1
    const int ob0 = rb0 >> 2;
    const float4* P4  = (const float4*)P;
    const float4* pb4 = (const float4*)projb;
    float4* out4 = (float4*)out;
    const float4 bias0 = pb4[lane];
    const float4 bias1 = pb4[64 + lane];
#pragma unroll 2
    for (int r = 0; r < 8; r++) {
        const int ig0 = __shfl(minia, r * 4 + 0);
        const int ig1 = __shfl(minia, r * 4 + 1);
        const int ig2 = __shfl(minia, r * 4 + 2);
        const int ig3 = __shfl(minia, r * 4 + 3);
#pragma unroll
        for (int p = 0; p < 2; p++) {
            const int c4 = p * 64 + lane;
            float4 acc = p ? bias1 : bias0;
            float4 a0 = P4[(size_t)ig0 * 128 + c4];
            float4 a1 = P4[ 65536 + (size_t)ig1 * 128 + c4];
            float4 a2 = P4[131072 + (size_t)ig2 * 128 + c4];
            float4 a3 = P4[196608 + (size_t)ig3 * 128 + c4];
            acc.x += a0.x + a1.x + a2.x + a3.x;
            acc.y += a0.y + a1.y + a2.y + a3.y;
            acc.z += a0.z + a1.z + a2.z + a3.z;
            acc.w += a0.w + a1.w + a2.w + a3.w;
            out4[(size_t)(ob0 + r) * 128 + c4] = acc;
        }
    }
#pragma unroll 2
    for (int r = 0; r < 8; r++) {
        const int ig0 = __shfl(minib, r * 4 + 0);
        const int ig1 = __shfl(minib, r * 4 + 1);
        const int ig2 = __shfl(minib, r * 4 + 2);
        const int ig3 = __shfl(minib, r * 4 + 3);
#pragma unroll
        for (int p = 0; p < 2; p++) {
            const int c4 = p * 64 + lane;
            float4 acc = p ? bias1 : bias0;
            float4 a0 = P4[(size_t)ig0 * 128 + c4];
            float4 a1 = P4[ 65536 + (size_t)ig1 * 128 + c4];
            float4 a2 = P4[131072 + (size_t)ig2 * 128 + c4];
            float4 a3 = P4[196608 + (size_t)ig3 * 128 + c4];
            acc.x += a0.x + a1.x + a2.x + a3.x;
            acc.y += a0.y + a1.y + a2.y + a3.y;
            acc.z += a0.z + a1.z + a2.z + a3.z;
            acc.w += a0.w + a1.w + a2.w + a3.w;
            out4[(size_t)(ob0 + 32 + r) * 128 + c4] = acc;
        }
    }

    // diff partial: ||x||^2 + min proxy for both row-groups, lanes<32 only.
    // Fire-and-forget (no return value -> wave does not wait), after stores.
    float xfa = xna + __shfl_xor(xna, 32);
    float xfb = xnb + __shfl_xor(xnb, 32);
    float v = (lane < 32) ? (xfa + minva + xfb + minvb) : 0.0f;
#pragma unroll
    for (int off = 32; off; off >>= 1) v += __shfl_down(v, off);
    if (lane == 0) atomicAdd(ws_diff, v);
}

// ---------------------------------------------------------------------------
__global__ void finalize_kernel(const float* __restrict__ ws_diff,
                                float* __restrict__ diff_out) {
    // diff = 12.5 * (sum ||x||^2 + sum min(||e||^2 - 2x.e)) / (NROWS*D)
    diff_out[0] = 12.5f * ws_diff[0] * (1.0f / 16777216.0f);
}

// ---------------------------------------------------------------------------
extern "C" void kernel_launch(void* const* d_in, const int* in_sizes, int n_in,
                              void* d_out, int out_size, void* d_ws, size_t ws_size,
                              hipStream_t stream) {
    const float* z     = (const float*)d_in[0];
    const float* embed = (const float*)d_in[1];
    const float* projw = (const float*)d_in[2];
    const float* projb = (const float*)d_in[3];

    float* out      = (float*)d_out;
    float* diff_out = out + OUT_ELEMS;
    float* ind_f    = out + OUT_ELEMS + 1;

    char* wsb = (char*)d_ws;
    float* ws_diff = (float*)wsb;
    float* entab = (float*)(wsb + 1024);
    unsigned short* esw = (unsigned short*)(wsb + 4096);
    float* P = (float*)(wsb + 266240);

    prep_kernel<<<80, 256, 0, stream>>>(embed, projw, esw, entab, ws_diff, P);
    argmin_fused_kernel<<<NROWS / 256, 256, 0, stream>>>(z, esw, entab, P, projb,
                                                         ws_diff, ind_f, out);
    finalize_kernel<<<1, 1, 0, stream>>>(ws_diff, diff_out);
}

// Round 7
// 221.698 us; speedup vs baseline: 1.0599x; 1.0599x over previous
//
#include <hip/hip_runtime.h>

// Problem constants (B=8, H=4096, C=512, GROUPS=4)
constexpr int D         = 128;        // d = C/GROUPS
constexpr int NE        = 512;        // n_embed
constexpr int NROWS     = 131072;     // B*H*GROUPS
constexpr int CC        = 512;        // C
constexpr int OUT_ELEMS = 16777216;   // MROWS*CC

// ws layout (bytes):
//   [0]                 : float diff accumulator
//   [1024, +2048)       : entab - ||e_j||^2 fp32, 512 floats
//   [4096, +262144)     : esw - 16 chunks x 16384 B:
//        [0,8192)   Eh : fp16(-2E), MFMA A-frag layout
//        [8192,16384) El: fp16((-2E - Eh)*2048)
//   [266240, +4194304)  : P[4][512][512] fp32

using half8  = __attribute__((ext_vector_type(8))) _Float16;
using f32x16 = __attribute__((ext_vector_type(16))) float;
using f32x4  = __attribute__((ext_vector_type(4))) float;   // native: OK for
                                                            // nontemporal builtins

// fp16 min normal: leading term below this is zeroed so the (possibly
// flushed-by-MFMA) denormal carries nothing; residual then holds it all.
#define F16_MINNORM 6.103515625e-05f

// plain 2-term f16 split of 8 floats: v = t1 + t2/2048 (+ ~2^-21 rel)
__device__ __forceinline__ void split8v(f32x4 a, f32x4 b,
                                        half8& t1, half8& t2) {
    float v[8] = {a[0], a[1], a[2], a[3], b[0], b[1], b[2], b[3]};
#pragma unroll
    for (int i = 0; i < 8; i++) {
        float vc = (__builtin_fabsf(v[i]) < F16_MINNORM) ? 0.0f : v[i];
        _Float16 h = (_Float16)vc;
        float r = v[i] - (float)h;
        t1[i] = h;
        t2[i] = (_Float16)(r * 2048.0f);
    }
}

// ---------------------------------------------------------------------------
// Kernel 0 (fused): blocks [0,64)  = MFMA pgemm  P[g][j][c] = sum_k E[j,k]*W[c,g*128+k]
//                   blocks [64,80) = eprep (fp16 split of -2E + ||e||^2 table)
// launch_bounds(256,1): pgemm waves hold ~210 VGPR (wh/wl + eh/el + accs);
// round 5's (256,4) = 128-VGPR cap caused scratch spills in the q-loop.
__launch_bounds__(256, 1)
__global__ void prep_kernel(const float* __restrict__ embed,
                            const float* __restrict__ projw,
                            unsigned short* __restrict__ esw,
                            float* __restrict__ entab,
                            float* __restrict__ ws_diff,
                            float* __restrict__ P) {
    const int tid = threadIdx.x;

    if (blockIdx.x >= 64) {
        // ---- eprep body ----
        const int chunk = blockIdx.x - 64;
        const int cl = tid >> 3;    // code in chunk (0..31) == A-row == lane&31
        const int seg = tid & 7;    // k-group of 16 (== kk)
        const float* src = embed + (size_t)(chunk * 32 + cl) * D + seg * 16;
        unsigned short* cb = esw + (size_t)chunk * 8192;  // shorts per chunk

        float ss = 0.f;
#pragma unroll
        for (int g2 = 0; g2 < 2; g2++) {   // g2 == h5 (k-half of the MFMA slice)
            f32x4 a = ((const f32x4*)src)[g2 * 2 + 0];
            f32x4 b = ((const f32x4*)src)[g2 * 2 + 1];
            float v[8] = {a[0], a[1], a[2], a[3], b[0], b[1], b[2], b[3]};
            half8 t1, t2;
#pragma unroll
            for (int i = 0; i < 8; i++) {
                ss += v[i] * v[i];
                float m2 = -2.0f * v[i];
                float m2c = (__builtin_fabsf(m2) < F16_MINNORM) ? 0.0f : m2;
                _Float16 h = (_Float16)m2c;
                float r = m2 - (float)h;
                t1[i] = h;
                t2[i] = (_Float16)(r * 2048.0f);   // scaled residual, fp16-normal
            }
            const int idx = seg * 512 + g2 * 256 + cl * 8;
            *(half8*)(cb + idx) = t1;          // Eh
            *(half8*)(cb + 4096 + idx) = t2;   // El
        }
        ss += __shfl_down(ss, 4, 8);
        ss += __shfl_down(ss, 2, 8);
        ss += __shfl_down(ss, 1, 8);
        if (seg == 0) entab[chunk * 32 + cl] = ss;
        if (chunk == 0 && tid == 0) ws_diff[0] = 0.0f;
        return;
    }

    // ---- MFMA pgemm: wave-job = (g, cblk, quad) ----
    const int lane = tid & 63;
    const int wave = tid >> 6;
    const int h5 = lane >> 5, l5 = lane & 31;
    const int job  = blockIdx.x * 4 + wave;   // 0..255
    const int g    = job >> 6;                // 0..3
    const int cblk = (job >> 2) & 15;         // 0..15 (32 c's each)
    const int quad = job & 3;                 // 0..3  (4 chunks of 32 codes)

    // W fragments (B-operand): lane holds W row (cblk*32+l5), k = kk*16+h5*8+j
    half8 wh[8], wl[8];
    {
        const float* wr = projw + (size_t)(cblk * 32 + l5) * CC + g * D + h5 * 8;
#pragma unroll
        for (int kk = 0; kk < 8; kk++) {
            f32x4 a = *(const f32x4*)(wr + kk * 16);
            f32x4 b = *(const f32x4*)(wr + kk * 16 + 4);
            split8v(a, b, wh[kk], wl[kk]);
        }
    }

#pragma unroll 1
    for (int q = 0; q < 4; q++) {
        const int ch = quad * 4 + q;
        // E fragments (A-operand): lane holds code row (ch*32+l5), same k map
        half8 eh[8], el[8];
        {
            const float* er = embed + (size_t)(ch * 32 + l5) * D + h5 * 8;
#pragma unroll
            for (int kk = 0; kk < 8; kk++) {
                f32x4 a = *(const f32x4*)(er + kk * 16);
                f32x4 b = *(const f32x4*)(er + kk * 16 + 4);
                split8v(a, b, eh[kk], el[kk]);
            }
        }
        f32x16 accA = (f32x16)(0.0f), accB = (f32x16)(0.0f);
#pragma unroll
        for (int kk = 0; kk < 8; kk++) {
            accA = __builtin_amdgcn_mfma_f32_32x32x16_f16(eh[kk], wh[kk], accA, 0, 0, 0);
            accB = __builtin_amdgcn_mfma_f32_32x32x16_f16(eh[kk], wl[kk], accB, 0, 0, 0);
            accB = __builtin_amdgcn_mfma_f32_32x32x16_f16(el[kk], wh[kk], accB, 0, 0, 0);
        }
        // C layout: row j = (r&3)+8*(r>>2)+4*h5, col c = l5 (coalesced stores)
#pragma unroll
        for (int r = 0; r < 16; r++) {
            const int jl = (r & 3) + 8 * (r >> 2) + 4 * h5;
            P[(size_t)g * 262144 + (size_t)(ch * 32 + jl) * CC + cblk * 32 + l5] =
                fmaf(accB[r], 4.8828125e-4f, accA[r]);
        }
    }
}

// ---------------------------------------------------------------------------
// Kernel 1: fused MFMA argmin + projection epilogue, T3/T4 pipelined staging
// (round-4 R=1 shape: 3 blocks/CU, 3-slot ring, counted vmcnt, no fence).
// z loads and out stores are NONTEMPORAL (no-allocate) so the 128 MB
// read-once/write-once streams stop evicting esw (256 KB) / P (4 MB) from the
// per-XCD L2 -> stage waits hit L2 (~200cy) not L3 (~900cy), P-gathers stay
// L2-fast. s_setprio(1) wraps the MFMA cluster (T5).
__global__ __launch_bounds__(256, 3)
void argmin_fused_kernel(const float* __restrict__ z,
                         const unsigned short* __restrict__ esw,
                         const float* __restrict__ entab,
                         const float* __restrict__ P,
                         const float* __restrict__ projb,
                         float* __restrict__ ws_diff,
                         float* __restrict__ ind_f,
                         float* __restrict__ out) {
    __shared__ __align__(16) unsigned char ebuf[3 * 16384];   // 3-slot chunk ring
    __shared__ __align__(16) float entab_s[512];
    const int tid = threadIdx.x;
    const int lane = tid & 63;
    const int wave = tid >> 6;
    const int h5 = lane >> 5, l5 = lane & 31;
    const int rb = blockIdx.x * 128 + wave * 32;

    // stage chunk c into ring slot b (16384 B; 4096 B per wave, 4 x 1024 B)
    // LDS dst is wave-uniform base; HW adds lane*16. Global src is per-lane.
    auto stage = [&](int c, int b) {
        const unsigned char* s = (const unsigned char*)esw + (size_t)c * 16384 +
                                 wave * 4096 + lane * 16;
        unsigned char* d = &ebuf[b * 16384 + wave * 4096];
#pragma unroll
        for (int it = 0; it < 4; it++)
            __builtin_amdgcn_global_load_lds(
                (const __attribute__((address_space(1))) unsigned int*)(s + it * 1024),
                (__attribute__((address_space(3))) unsigned int*)(d + it * 1024),
                16, 0, 0);
    };

    // ---- prologue: issue entab->LDS, stage(0), stage(1); then z load+convert.
    if (tid < 128)
        __builtin_amdgcn_global_load_lds(
            (const __attribute__((address_space(1))) unsigned int*)(entab + tid * 4),
            (__attribute__((address_space(3))) unsigned int*)(entab_s + tid * 4),
            16, 0, 0);
    stage(0, 0);
    stage(1, 1);

    // X fragments: B-frag for kk holds X[n=l5][k = kk*16 + h5*8 + j]
    // Nontemporal: z is read-once; do not pollute L2.
    half8 x1[8], x2[8];
    float xn = 0.f;
    {
        const f32x4* zr = (const f32x4*)(z + (size_t)(rb + l5) * D + h5 * 8);
#pragma unroll
        for (int kk = 0; kk < 8; kk++) {
            f32x4 a = __builtin_nontemporal_load(zr + kk * 4);
            f32x4 b = __builtin_nontemporal_load(zr + kk * 4 + 1);
            xn += a[0]*a[0] + a[1]*a[1] + a[2]*a[2] + a[3]*a[3] +
                  b[0]*b[0] + b[1]*b[1] + b[2]*b[2] + b[3]*b[3];
            split8v(a, b, x1[kk], x2[kk]);
        }
    }

    float minv = 3.0e38f;
    int   mini = 0;

    int bs = 0;                    // ring slot of chunk c
    int ts = 2;                    // ring slot of chunk c+2
#pragma unroll 1
    for (int c = 0; c < 16; c++) {
        // chunk c's stage loads done (leave c+1's 4 in flight); all-waves align
        if (c < 15) { asm volatile("s_waitcnt vmcnt(4)" ::: "memory"); }
        else        { asm volatile("s_waitcnt vmcnt(0)" ::: "memory"); }
        __builtin_amdgcn_s_barrier();
        __builtin_amdgcn_sched_barrier(0);
        // safe to overwrite slot ts (last read in compute(c-1), all waves past)
        if (c < 14) stage(c + 2, ts);

        const unsigned char* ldsb = &ebuf[bs * 16384];

        f32x16 accA = (f32x16)(0.0f), accB = (f32x16)(0.0f);
        __builtin_amdgcn_s_setprio(1);
#pragma unroll
        for (int kk = 0; kk < 8; kk++) {
            const int fo = kk * 1024 + h5 * 512 + l5 * 16;
            half8 e1 = *(const half8*)(ldsb + fo);
            half8 e2 = *(const half8*)(ldsb + 8192 + fo);
            accA = __builtin_amdgcn_mfma_f32_32x32x16_f16(e1, x1[kk], accA, 0, 0, 0);
            accB = __builtin_amdgcn_mfma_f32_32x32x16_f16(e1, x2[kk], accB, 0, 0, 0);
            accB = __builtin_amdgcn_mfma_f32_32x32x16_f16(e2, x1[kk], accB, 0, 0, 0);
        }
        __builtin_amdgcn_s_setprio(0);

        // ||e||^2 from LDS (broadcast reads, no vmcnt traffic)
        f32x4 enr[4];
#pragma unroll
        for (int u = 0; u < 4; u++)
            enr[u] = *(const f32x4*)&entab_s[c * 32 + h5 * 4 + u * 8];

        // scan: dist = accA + 2^-11 * accB + ||e||^2 ; monotone code order
        const int cb2 = c * 32 + h5 * 4;
#pragma unroll
        for (int r = 0; r < 16; r++) {
            const float en = enr[r >> 2][r & 3];
            const int cand = cb2 + (r & 3) + 8 * (r >> 2);
            float d0 = fmaf(accB[r], 4.8828125e-4f, accA[r]) + en;
            if (d0 < minv) { minv = d0; mini = cand; }  // strict < keeps first
        }
        bs = (bs == 2) ? 0 : bs + 1;
        ts = (ts == 2) ? 0 : ts + 1;
    }

    // merge the two half-wave code sets for the same x-row (col = lane&31)
    {
        float ov = __shfl_xor(minv, 32);
        int oi = __shfl_xor(mini, 32);
        if (ov < minv || (ov == minv && oi < mini)) { minv = ov; mini = oi; }
    }
    if (lane < 32) ind_f[rb + l5] = (float)mini;

    // ---- fused projection epilogue (wave-local, indices via shuffle) ----
    // wave owns out-rows [ob, ob+8); out[m,c] = sum_g P[g][ind[m,g]][c] + b[c]
    // P-gathers cached (L2-resident now); out stores nontemporal (write-once).
    const int ob = rb >> 2;
    const f32x4* P4  = (const f32x4*)P;
    const f32x4* pb4 = (const f32x4*)projb;
    f32x4* out4 = (f32x4*)out;
    const f32x4 bias0 = pb4[lane];
    const f32x4 bias1 = pb4[64 + lane];
#pragma unroll 2
    for (int r = 0; r < 8; r++) {
        const int ig0 = __shfl(mini, r * 4 + 0);
        const int ig1 = __shfl(mini, r * 4 + 1);
        const int ig2 = __shfl(mini, r * 4 + 2);
        const int ig3 = __shfl(mini, r * 4 + 3);
#pragma unroll
        for (int p = 0; p < 2; p++) {
            const int c4 = p * 64 + lane;
            f32x4 acc = p ? bias1 : bias0;
            f32x4 a0 = P4[(size_t)ig0 * 128 + c4];
            f32x4 a1 = P4[ 65536 + (size_t)ig1 * 128 + c4];
            f32x4 a2 = P4[131072 + (size_t)ig2 * 128 + c4];
            f32x4 a3 = P4[196608 + (size_t)ig3 * 128 + c4];
            acc += a0 + a1 + a2 + a3;
            __builtin_nontemporal_store(acc, &out4[(size_t)(ob + r) * 128 + c4]);
        }
    }

    // diff partial: ||x||^2 (both k-halves) + min proxy, lanes<32 only.
    // Fire-and-forget (no return value -> wave does not wait), after stores.
    float xfull = xn + __shfl_xor(xn, 32);
    float v = (lane < 32) ? (xfull + minv) : 0.0f;
#pragma unroll
    for (int off = 32; off; off >>= 1) v += __shfl_down(v, off);
    if (lane == 0) atomicAdd(ws_diff, v);
}

// ---------------------------------------------------------------------------
__global__ void finalize_kernel(const float* __restrict__ ws_diff,
                                float* __restrict__ diff_out) {
    // diff = 12.5 * (sum ||x||^2 + sum min(||e||^2 - 2x.e)) / (NROWS*D)
    diff_out[0] = 12.5f * ws_diff[0] * (1.0f / 16777216.0f);
}

// ---------------------------------------------------------------------------
extern "C" void kernel_launch(void* const* d_in, const int* in_sizes, int n_in,
                              void* d_out, int out_size, void* d_ws, size_t ws_size,
                              hipStream_t stream) {
    const float* z     = (const float*)d_in[0];
    const float* embed = (const float*)d_in[1];
    const float* projw = (const float*)d_in[2];
    const float* projb = (const float*)d_in[3];

    float* out      = (float*)d_out;
    float* diff_out = out + OUT_ELEMS;
    float* ind_f    = out + OUT_ELEMS + 1;

    char* wsb = (char*)d_ws;
    float* ws_diff = (float*)wsb;
    float* entab = (float*)(wsb + 1024);
    unsigned short* esw = (unsigned short*)(wsb + 4096);
    float* P = (float*)(wsb + 266240);

    prep_kernel<<<80, 256, 0, stream>>>(embed, projw, esw, entab, ws_diff, P);
    argmin_fused_kernel<<<NROWS / 128, 256, 0, stream>>>(z, esw, entab, P, projb,
                                                         ws_diff, ind_f, out);
    finalize_kernel<<<1, 1, 0, stream>>>(ws_diff, diff_out);
}

// Round 8
// 212.102 us; speedup vs baseline: 1.1079x; 1.0452x over previous
//
#include <hip/hip_runtime.h>

// Problem constants (B=8, H=4096, C=512, GROUPS=4)
constexpr int D         = 128;        // d = C/GROUPS
constexpr int NE        = 512;        // n_embed
constexpr int NROWS     = 131072;     // B*H*GROUPS
constexpr int CC        = 512;        // C
constexpr int OUT_ELEMS = 16777216;   // MROWS*CC

// ws layout (bytes):
//   [0]                 : float diff accumulator
//   [1024, +2048)       : entab - ||e_j||^2 fp32, 512 floats
//   [4096, +262144)     : esw - 16 chunks x 16384 B:
//        [0,8192)   Eh : fp16(-2E), MFMA A-frag layout
//        [8192,16384) El: fp16((-2E - Eh)*2048)
//   [266240, +4194304)  : P[4][512][512] fp32

using half8  = __attribute__((ext_vector_type(8))) _Float16;
using f32x16 = __attribute__((ext_vector_type(16))) float;
using f32x4  = __attribute__((ext_vector_type(4))) float;

// fp16 min normal: leading term below this is zeroed so the (possibly
// flushed-by-MFMA) denormal carries nothing; residual then holds it all.
#define F16_MINNORM 6.103515625e-05f

// plain 2-term f16 split of 8 floats: v = t1 + t2/2048 (+ ~2^-21 rel)
__device__ __forceinline__ void split8v(f32x4 a, f32x4 b,
                                        half8& t1, half8& t2) {
    float v[8] = {a[0], a[1], a[2], a[3], b[0], b[1], b[2], b[3]};
#pragma unroll
    for (int i = 0; i < 8; i++) {
        float vc = (__builtin_fabsf(v[i]) < F16_MINNORM) ? 0.0f : v[i];
        _Float16 h = (_Float16)vc;
        float r = v[i] - (float)h;
        t1[i] = h;
        t2[i] = (_Float16)(r * 2048.0f);
    }
}

// ---------------------------------------------------------------------------
// K0: eprep — fp16 split of -2E into MFMA A-frag layout + ||e||^2 table.
// The ONLY producer the argmin blocks depend on; kept tiny (16 blocks) so the
// serialized prefix is ~3 us instead of the whole prep pipeline.
__global__ void eprep_kernel(const float* __restrict__ embed,
                             unsigned short* __restrict__ esw,
                             float* __restrict__ entab,
                             float* __restrict__ ws_diff) {
    const int chunk = blockIdx.x;
    const int tid = threadIdx.x;
    const int cl = tid >> 3;    // code in chunk (0..31) == A-row == lane&31
    const int seg = tid & 7;    // k-group of 16 (== kk)
    const float* src = embed + (size_t)(chunk * 32 + cl) * D + seg * 16;
    unsigned short* cb = esw + (size_t)chunk * 8192;  // shorts per chunk

    float ss = 0.f;
#pragma unroll
    for (int g2 = 0; g2 < 2; g2++) {   // g2 == h5 (k-half of the MFMA slice)
        f32x4 a = ((const f32x4*)src)[g2 * 2 + 0];
        f32x4 b = ((const f32x4*)src)[g2 * 2 + 1];
        float v[8] = {a[0], a[1], a[2], a[3], b[0], b[1], b[2], b[3]};
        half8 t1, t2;
#pragma unroll
        for (int i = 0; i < 8; i++) {
            ss += v[i] * v[i];
            float m2 = -2.0f * v[i];
            float m2c = (__builtin_fabsf(m2) < F16_MINNORM) ? 0.0f : m2;
            _Float16 h = (_Float16)m2c;
            float r = m2 - (float)h;
            t1[i] = h;
            t2[i] = (_Float16)(r * 2048.0f);   // scaled residual, fp16-normal
        }
        const int idx = seg * 512 + g2 * 256 + cl * 8;
        *(half8*)(cb + idx) = t1;          // Eh
        *(half8*)(cb + 4096 + idx) = t2;   // El
    }
    ss += __shfl_down(ss, 4, 8);
    ss += __shfl_down(ss, 2, 8);
    ss += __shfl_down(ss, 1, 8);
    if (seg == 0) entab[chunk * 32 + cl] = ss;
    if (chunk == 0 && tid == 0) ws_diff[0] = 0.0f;
}

// ---------------------------------------------------------------------------
// K1: blocks [0,1024)   = argmin (MFMA distance scan, T3/T4 pipelined staging)
//     blocks [1024,1088)= MFMA pgemm P[g][j][c] = sum_k E[j,k]*W[c,g*128+k]
// The two families are INDEPENDENT (no cross-block ordering): pgemm's P is
// consumed only by K2. pgemm's latency-bound work hides inside argmin's
// ~100 us. launch_bounds(256,3) caps VGPR ~168 so argmin keeps 3 blocks/CU
// (its path uses 84); pgemm may spill slightly — it's 64 blocks, hidden.
__global__ __launch_bounds__(256, 3)
void main_kernel(const float* __restrict__ z,
                 const unsigned short* __restrict__ esw,
                 const float* __restrict__ entab,
                 const float* __restrict__ embed,
                 const float* __restrict__ projw,
                 float* __restrict__ P,
                 float* __restrict__ ws_diff,
                 float* __restrict__ ind_f) {
    __shared__ __align__(16) unsigned char ebuf[3 * 16384];   // 3-slot chunk ring
    __shared__ __align__(16) float entab_s[512];
    const int tid = threadIdx.x;
    const int lane = tid & 63;
    const int wave = tid >> 6;
    const int h5 = lane >> 5, l5 = lane & 31;

    if (blockIdx.x >= 1024) {
        // ---- MFMA pgemm: wave-job = (g, cblk, quad) ----
        const int job  = (blockIdx.x - 1024) * 4 + wave;   // 0..255
        const int g    = job >> 6;                // 0..3
        const int cblk = (job >> 2) & 15;         // 0..15 (32 c's each)
        const int quad = job & 3;                 // 0..3  (4 chunks of 32 codes)

        // W fragments (B-operand): lane holds W row (cblk*32+l5)
        half8 wh[8], wl[8];
        {
            const float* wr = projw + (size_t)(cblk * 32 + l5) * CC + g * D + h5 * 8;
#pragma unroll
            for (int kk = 0; kk < 8; kk++) {
                f32x4 a = *(const f32x4*)(wr + kk * 16);
                f32x4 b = *(const f32x4*)(wr + kk * 16 + 4);
                split8v(a, b, wh[kk], wl[kk]);
            }
        }
#pragma unroll 1
        for (int q = 0; q < 4; q++) {
            const int ch = quad * 4 + q;
            const float* er = embed + (size_t)(ch * 32 + l5) * D + h5 * 8;
            f32x16 accA = (f32x16)(0.0f), accB = (f32x16)(0.0f);
#pragma unroll
            for (int kk = 0; kk < 8; kk++) {
                f32x4 a = *(const f32x4*)(er + kk * 16);
                f32x4 b = *(const f32x4*)(er + kk * 16 + 4);
                half8 eh, el;
                split8v(a, b, eh, el);
                accA = __builtin_amdgcn_mfma_f32_32x32x16_f16(eh, wh[kk], accA, 0, 0, 0);
                accB = __builtin_amdgcn_mfma_f32_32x32x16_f16(eh, wl[kk], accB, 0, 0, 0);
                accB = __builtin_amdgcn_mfma_f32_32x32x16_f16(el, wh[kk], accB, 0, 0, 0);
            }
            // C layout: row j = (r&3)+8*(r>>2)+4*h5, col c = l5 (coalesced)
#pragma unroll
            for (int r = 0; r < 16; r++) {
                const int jl = (r & 3) + 8 * (r >> 2) + 4 * h5;
                P[(size_t)g * 262144 + (size_t)(ch * 32 + jl) * CC + cblk * 32 + l5] =
                    fmaf(accB[r], 4.8828125e-4f, accA[r]);
            }
        }
        return;
    }

    // ---- argmin body (round-7 proven structure, epilogue removed) ----
    const int rb = blockIdx.x * 128 + wave * 32;

    // stage chunk c into ring slot b (16384 B; 4096 B per wave, 4 x 1024 B)
    auto stage = [&](int c, int b) {
        const unsigned char* s = (const unsigned char*)esw + (size_t)c * 16384 +
                                 wave * 4096 + lane * 16;
        unsigned char* d = &ebuf[b * 16384 + wave * 4096];
#pragma unroll
        for (int it = 0; it < 4; it++)
            __builtin_amdgcn_global_load_lds(
                (const __attribute__((address_space(1))) unsigned int*)(s + it * 1024),
                (__attribute__((address_space(3))) unsigned int*)(d + it * 1024),
                16, 0, 0);
    };

    if (tid < 128)
        __builtin_amdgcn_global_load_lds(
            (const __attribute__((address_space(1))) unsigned int*)(entab + tid * 4),
            (__attribute__((address_space(3))) unsigned int*)(entab_s + tid * 4),
            16, 0, 0);
    stage(0, 0);
    stage(1, 1);

    // X fragments: B-frag for kk holds X[n=l5][k = kk*16 + h5*8 + j]
    half8 x1[8], x2[8];
    float xn = 0.f;
    {
        const f32x4* zr = (const f32x4*)(z + (size_t)(rb + l5) * D + h5 * 8);
#pragma unroll
        for (int kk = 0; kk < 8; kk++) {
            f32x4 a = __builtin_nontemporal_load(zr + kk * 4);
            f32x4 b = __builtin_nontemporal_load(zr + kk * 4 + 1);
            xn += a[0]*a[0] + a[1]*a[1] + a[2]*a[2] + a[3]*a[3] +
                  b[0]*b[0] + b[1]*b[1] + b[2]*b[2] + b[3]*b[3];
            split8v(a, b, x1[kk], x2[kk]);
        }
    }

    float minv = 3.0e38f;
    int   mini = 0;

    int bs = 0;                    // ring slot of chunk c
    int ts = 2;                    // ring slot of chunk c+2
#pragma unroll 1
    for (int c = 0; c < 16; c++) {
        // chunk c's stage loads done (leave c+1's 4 in flight); all-waves align
        if (c < 15) { asm volatile("s_waitcnt vmcnt(4)" ::: "memory"); }
        else        { asm volatile("s_waitcnt vmcnt(0)" ::: "memory"); }
        __builtin_amdgcn_s_barrier();
        __builtin_amdgcn_sched_barrier(0);
        if (c < 14) stage(c + 2, ts);

        const unsigned char* ldsb = &ebuf[bs * 16384];

        f32x16 accA = (f32x16)(0.0f), accB = (f32x16)(0.0f);
        __builtin_amdgcn_s_setprio(1);
#pragma unroll
        for (int kk = 0; kk < 8; kk++) {
            const int fo = kk * 1024 + h5 * 512 + l5 * 16;
            half8 e1 = *(const half8*)(ldsb + fo);
            half8 e2 = *(const half8*)(ldsb + 8192 + fo);
            accA = __builtin_amdgcn_mfma_f32_32x32x16_f16(e1, x1[kk], accA, 0, 0, 0);
            accB = __builtin_amdgcn_mfma_f32_32x32x16_f16(e1, x2[kk], accB, 0, 0, 0);
            accB = __builtin_amdgcn_mfma_f32_32x32x16_f16(e2, x1[kk], accB, 0, 0, 0);
        }
        __builtin_amdgcn_s_setprio(0);

        // ||e||^2 from LDS (broadcast reads, no vmcnt traffic)
        f32x4 enr[4];
#pragma unroll
        for (int u = 0; u < 4; u++)
            enr[u] = *(const f32x4*)&entab_s[c * 32 + h5 * 4 + u * 8];

        // scan: dist = accA + 2^-11 * accB + ||e||^2 ; monotone code order
        const int cb2 = c * 32 + h5 * 4;
#pragma unroll
        for (int r = 0; r < 16; r++) {
            const float en = enr[r >> 2][r & 3];
            const int cand = cb2 + (r & 3) + 8 * (r >> 2);
            float d0 = fmaf(accB[r], 4.8828125e-4f, accA[r]) + en;
            if (d0 < minv) { minv = d0; mini = cand; }  // strict < keeps first
        }
        bs = (bs == 2) ? 0 : bs + 1;
        ts = (ts == 2) ? 0 : ts + 1;
    }

    // merge the two half-wave code sets for the same x-row (col = lane&31)
    {
        float ov = __shfl_xor(minv, 32);
        int oi = __shfl_xor(mini, 32);
        if (ov < minv || (ov == minv && oi < mini)) { minv = ov; mini = oi; }
    }
    if (lane < 32) ind_f[rb + l5] = (float)mini;

    // diff partial: ||x||^2 (both k-halves) + min proxy, lanes<32 only.
    float xfull = xn + __shfl_xor(xn, 32);
    float v = (lane < 32) ? (xfull + minv) : 0.0f;
#pragma unroll
    for (int off = 32; off; off >>= 1) v += __shfl_down(v, off);
    if (lane == 0) atomicAdd(ws_diff, v);
}

// ---------------------------------------------------------------------------
// K2: projection epilogue + folded finalize.
// out[m,c] = sum_g P[g][ind[m,g]][c] + b[c]. 512 blocks x 32 out-rows.
// Pure-memory: 128 KB P-gather + 32 KB nt out-store per block.
__global__ __launch_bounds__(256)
void outproj_kernel(const float* __restrict__ P,
                    const float* __restrict__ projb,
                    const float* __restrict__ ind_f,
                    const float* __restrict__ ws_diff,
                    float* __restrict__ out,
                    float* __restrict__ diff_out) {
    __shared__ int ind_s[128];
    const int tid = threadIdx.x;
    const int mb = blockIdx.x * 32;

    if (blockIdx.x == 0 && tid == 0)
        diff_out[0] = 12.5f * ws_diff[0] * (1.0f / 16777216.0f);

    if (tid < 128) ind_s[tid] = (int)ind_f[mb * 4 + tid];
    __syncthreads();

    const int c4 = tid & 127;
    const int mh = (tid >> 7) * 16;   // 0 or 16
    const f32x4* P4  = (const f32x4*)P;
    const f32x4 bias = ((const f32x4*)projb)[c4];
    f32x4* out4 = (f32x4*)out;
#pragma unroll 4
    for (int u = 0; u < 16; u++) {
        const int ml = mh + u;
        f32x4 acc = bias;
#pragma unroll
        for (int g = 0; g < 4; g++) {
            const int ig = ind_s[ml * 4 + g];
            acc += P4[(size_t)g * 65536 + (size_t)ig * 128 + c4];
        }
        __builtin_nontemporal_store(acc, &out4[(size_t)(mb + ml) * 128 + c4]);
    }
}

// ---------------------------------------------------------------------------
extern "C" void kernel_launch(void* const* d_in, const int* in_sizes, int n_in,
                              void* d_out, int out_size, void* d_ws, size_t ws_size,
                              hipStream_t stream) {
    const float* z     = (const float*)d_in[0];
    const float* embed = (const float*)d_in[1];
    const float* projw = (const float*)d_in[2];
    const float* projb = (const float*)d_in[3];

    float* out      = (float*)d_out;
    float* diff_out = out + OUT_ELEMS;
    float* ind_f    = out + OUT_ELEMS + 1;

    char* wsb = (char*)d_ws;
    float* ws_diff = (float*)wsb;
    float* entab = (float*)(wsb + 1024);
    unsigned short* esw = (unsigned short*)(wsb + 4096);
    float* P = (float*)(wsb + 266240);

    eprep_kernel<<<16, 256, 0, stream>>>(embed, esw, entab, ws_diff);
    main_kernel<<<1088, 256, 0, stream>>>(z, esw, entab, embed, projw, P,
                                          ws_diff, ind_f);
    outproj_kernel<<<512, 256, 0, stream>>>(P, projb, ind_f, ws_diff, out,
                                            diff_out);
}